// Round 2
// 431.556 us; speedup vs baseline: 1.0192x; 1.0192x over previous
//
#include <hip/hip_runtime.h>

// CRC-24 encoder: out = [bits | parity(bits @ G mod 2)]
// BATCH=16384 rows, K=4096 bits/row, 24 CRC bits, OUTW=4120.
// Memory-bound: ~538 MB mandatory traffic -> ~90us floor at ~6 TB/s mixed.
// Timed harness window also contains ~334us of output re-poison fills (fixed).

constexpr int K       = 4096;
constexpr int CRC_LEN = 24;
constexpr int OUTW    = K + CRC_LEN;   // 4120 (divisible by 4 -> float4 stores ok)
constexpr int BATCH   = 16384;

// Native clang vector type: __builtin_nontemporal_* requires vector-of-scalar,
// not HIP_vector_type (a struct). Same 16B layout/codegen as float4.
typedef float f32x4 __attribute__((ext_vector_type(4)));

// Pack each g_mat row (24 floats of 0/1) into one 24-bit word. 4096 words -> d_ws.
__global__ void pack_gmat_kernel(const float* __restrict__ g,
                                 unsigned int* __restrict__ gm) {
    int i = blockIdx.x * blockDim.x + threadIdx.x;
    if (i < K) {
        unsigned int w = 0u;
        #pragma unroll
        for (int j = 0; j < CRC_LEN; ++j)
            w |= (g[i * CRC_LEN + j] != 0.0f ? 1u : 0u) << j;
        gm[i] = w;
    }
}

// One wave (64 lanes) per row; 4 waves (4 rows) per block; persistent blocks
// grid-stride over row-groups so the gm->LDS stage runs once per block.
// f32x4 nontemporal loads/stores; conditional XOR of packed gm words;
// wave-wide XOR butterfly; lanes 0..23 write the parity floats.
__global__ __launch_bounds__(256) void crc_encode_kernel(
        const float* __restrict__ in,
        const unsigned int* __restrict__ gm,
        float* __restrict__ out) {
    // Deinterleave gm by (i & 3): read pattern per ds_read is then stride-1
    // across lanes -> zero LDS bank conflicts (vs 8-way with flat layout).
    __shared__ unsigned int s_gm[4][K / 4];

    const int t = threadIdx.x;
    #pragma unroll
    for (int j = 0; j < K / 256; ++j) {
        int i = j * 256 + t;
        s_gm[i & 3][i >> 2] = gm[i];    // regular (cached) load: reused by all blocks
    }
    __syncthreads();

    const int wave = t >> 6;
    const int lane = t & 63;

    for (int grp = blockIdx.x; grp < BATCH / 4; grp += gridDim.x) {
        const int row = grp * 4 + wave;

        const f32x4* in4  = (const f32x4*)(in  + (size_t)row * K);
        f32x4*       out4 = (f32x4*)(out + (size_t)row * OUTW);

        unsigned int acc = 0u;
        #pragma unroll
        for (int it = 0; it < K / 256; ++it) {
            const int v = it * 64 + lane;                // f32x4 index within the row
            f32x4 b = __builtin_nontemporal_load(&in4[v]);
            __builtin_nontemporal_store(b, &out4[v]);    // fused copy (concat part 1)
            unsigned int w0 = s_gm[0][v];
            unsigned int w1 = s_gm[1][v];
            unsigned int w2 = s_gm[2][v];
            unsigned int w3 = s_gm[3][v];
            acc ^= (b.x != 0.0f) ? w0 : 0u;              // branchless v_cndmask + v_xor
            acc ^= (b.y != 0.0f) ? w1 : 0u;
            acc ^= (b.z != 0.0f) ? w2 : 0u;
            acc ^= (b.w != 0.0f) ? w3 : 0u;
        }

        // 64-lane XOR reduction
        #pragma unroll
        for (int off = 32; off >= 1; off >>= 1)
            acc ^= __shfl_xor(acc, off);

        if (lane < CRC_LEN)
            out[(size_t)row * OUTW + K + lane] = (float)((acc >> lane) & 1u);
    }
}

extern "C" void kernel_launch(void* const* d_in, const int* in_sizes, int n_in,
                              void* d_out, int out_size, void* d_ws, size_t ws_size,
                              hipStream_t stream) {
    const float* bits = (const float*)d_in[0];   // (16384, 4096) float32 of 0/1
    const float* g    = (const float*)d_in[1];   // (4096, 24)   float32 of 0/1
    float* out        = (float*)d_out;           // (16384, 4120) float32
    unsigned int* gm  = (unsigned int*)d_ws;     // 4096 packed words (16 KB)

    pack_gmat_kernel<<<K / 256, 256, 0, stream>>>(g, gm);
    // 2048 blocks = 8 blocks/CU x 256 CUs, exactly resident; each handles 2 groups.
    crc_encode_kernel<<<2048, 256, 0, stream>>>(bits, gm, out);
}